// Round 17
// baseline (229.564 us; speedup 1.0000x reference)
//
#include <hip/hip_runtime.h>
#include <stdint.h>

#define ROUNDS 64
#define HIDDEN 256
#define BATCH  65536
#define NSUP   8   // super-rounds: 8 chains of 8 rounds each

typedef int   v4i  __attribute__((ext_vector_type(4)));
typedef int   v8i  __attribute__((ext_vector_type(8)));
typedef float v16f __attribute__((ext_vector_type(16)));
typedef unsigned long long u64;

// ============================================================================
// PARTIAL ALGEBRAIC COLLAPSE (math+packing verified exact R12-R15). Each round
// is affine over GF(2): s' = Whar s ^ n. 64 rounds -> 8 super-rounds of 8:
// M_g = W_{8g+7}..W_{8g}, c_g folded constant; PROVEN R3 batch kernel runs 8
// rounds. Proven stack facts: intra-kernel cross-block sync ~100-150us
// (NEVER); launch boundary ~22us; fused per-CU bulk reads serialize (R15).
// R16/R17: 3-launch R13 skeleton + (a) NSUP=8 (R11-verified count=8 chain),
// (b) hash's initial state-pack moved into bitpack's launch as a bit-packed
// 2 MB spk array; hash8 stages T[0] via a bit->nibble spread (layout-identical
// to the verified pack, derivation below).
// ============================================================================

// ws layout (bytes)
#define SPK_OFF  0u         // state bits [b=512][KB=8][el=128] u32 = 2 MB
#define WB_OFF   2097152u   // W bits [64][256][4] u64 = 512 KB
#define NB_OFF   2621440u   // n bits [64][4] u64      = 2 KB
#define WPK_OFF  2623488u   // fp4 A-frags [g=8][mt=8][ks=4][lane=64][16B] = 256 KB
#define NF_OFF   2885632u   // noise floats [g=8][mt=8][lh=2][j=16] f32 = 8 KB

// sigma: nibble slot n (0..31) within a 32-k chunk holds logical k-offset
// rho(n). Applied identically to M-pack and state-pack so it cancels.
__host__ __device__ constexpr int rho(int n) {
  return 4 * (n >> 4) + (n & 3) + 8 * ((n >> 2) & 3);
}

// Per-C-slot bias (epilogue v_add_f32, IEEE-exact; round-1 FAILED note: bias
// must stay OUTSIDE the MFMA C-init; c in {0,1} as C-init is proven).
__host__ __device__ constexpr float bias_q(int q) {
  return (q == 0) ? 6291456.0f   // 1.5*2^22 -> parity at bit 1
       : (q == 1) ? 393216.0f    // 1.5*2^18 -> bit 5
       : (q == 2) ? 24576.0f     // 1.5*2^14 -> bit 9
                  : 1536.0f;     // 1.5*2^10 -> bit 13
}

// spread16: p bit i -> u64 bit 4i+1 (nibble i, bit 1 == the fp4 "+1" bit).
__device__ __forceinline__ u64 spread16(uint32_t p) {
  u64 t = p;
  t = (t | (t << 24)) & 0x000000FF000000FFull;
  t = (t | (t << 12)) & 0x000F000F000F000Full;
  t = (t | (t << 6))  & 0x0303030303030303ull;
  t = (t | (t << 3))  & 0x1111111111111111ull;
  return t << 1;
}

// ---- 1) bitpack: W->bits, noise->bits, AND sta->bit-packed spk (all
// independent full-grid blocks; replaces hash's in-kernel f32 state pack).
// spk entry (b,KB,el): u32, bit m = k4c*4+comp for float sta[el][KB*32+m].
__global__ __launch_bounds__(256) void bitpack(const float* __restrict__ mat,
                                               const float* __restrict__ noi,
                                               const float* __restrict__ sta,
                                               u64* __restrict__ wb,
                                               u64* __restrict__ nb,
                                               uint32_t* __restrict__ spk) {
  unsigned blk = blockIdx.x;
  if (blk < 16384u) {  // W bits
    unsigned tg = blk * 256u + threadIdx.x;
    u64 m = __ballot(mat[tg] != 0.f);
    if ((threadIdx.x & 63u) == 0u) wb[tg >> 6] = m;
    return;
  }
  if (blk < 16448u) {  // noise bits: 64*256
    unsigned tg = (blk - 16384u) * 256u + threadIdx.x;
    u64 m = __ballot(noi[tg] != 0.f);
    if ((threadIdx.x & 63u) == 0u) nb[tg >> 6] = m;
    return;
  }
  // sta bits: tg in [0, 524288): el = tg>>3, KB = tg&7; 8 independent float4
  // loads (MLP — R14/R15 lesson), 32 compares -> one u32.
  unsigned tg = (blk - 16448u) * 256u + threadIdx.x;
  unsigned el = tg >> 3, KB = tg & 7u;
  const float4* s4 = (const float4*)(sta + (size_t)el * 256 + KB * 32);
  float4 f[8];
#pragma unroll
  for (int q = 0; q < 8; ++q) f[q] = s4[q];
  uint32_t bits = 0;
#pragma unroll
  for (int q = 0; q < 8; ++q) {
    bits |= (f[q].x != 0.f ? 1u : 0u) << (4 * q + 0);
    bits |= (f[q].y != 0.f ? 1u : 0u) << (4 * q + 1);
    bits |= (f[q].z != 0.f ? 1u : 0u) << (4 * q + 2);
    bits |= (f[q].w != 0.f ? 1u : 0u) << (4 * q + 3);
  }
  spk[(el >> 7) * 1024u + KB * 128u + (el & 127u)] = bits;
}

// ---- chain compose on one block's LDS state (R8-R15-verified algorithm,
// rolling 1-step register prefetch). (A,a) <- compose maps [base, base+count).
__device__ __forceinline__ void fold_stream(u64 (&A)[256][5],
                                            u64 (&tbl)[64][16][5],
                                            u64 (&avec)[4],
                                            const u64* __restrict__ inM,
                                            const u64* __restrict__ inV,
                                            int base, int count,
                                            int tid, int w, int i) {
  A[i][w] = inM[(size_t)base * 1024 + i * 4 + w];
  if (tid < 4) avec[tid] = inV[base * 4 + tid];
  u64 brP[4];
  u64 bwP;
  {  // prefetch step j=1's B row / vector word
    const u64* Bm = inM + (size_t)(base + 1) * 1024;
#pragma unroll
    for (int q = 0; q < 4; ++q) brP[q] = Bm[i * 4 + q];
    bwP = (tid < 256) ? inV[(size_t)(base + 1) * 4 + (i >> 6)] : 0ull;
  }
  __syncthreads();

  for (int j = 1; j < count; ++j) {
    const u64 br0 = brP[0], br1 = brP[1], br2 = brP[2], br3 = brP[3];
    const u64 bwc = bwP;
    if (j + 1 < count) {  // next step's loads hide under the table build
      const u64* Bm = inM + (size_t)(base + j + 1) * 1024;
#pragma unroll
      for (int q = 0; q < 4; ++q) brP[q] = Bm[i * 4 + q];
      bwP = (tid < 256) ? inV[(size_t)(base + j + 1) * 4 + (i >> 6)] : 0ull;
    }
    u64 av0 = avec[0], av1 = avec[1], av2 = avec[2], av3 = avec[3];

    // build 4-bit combination table over A's rows (contraction index k)
    {
      const int c = tid >> 4, m = tid & 15;  // 1024 entries, 1/thread
      u64 t0 = 0, t1 = 0, t2 = 0, t3 = 0;
#pragma unroll
      for (int jj = 0; jj < 4; ++jj)
        if (m & (1 << jj)) {
          t0 ^= A[4 * c + jj][0]; t1 ^= A[4 * c + jj][1];
          t2 ^= A[4 * c + jj][2]; t3 ^= A[4 * c + jj][3];
        }
      tbl[c][m][0] = t0; tbl[c][m][1] = t1; tbl[c][m][2] = t2; tbl[c][m][3] = t3;
    }
    __syncthreads();

    // R[i] = XOR_{k: B[i][k]=1} A[k], word w — 4-way ILP over the 64 gathers
    const u64 brr[4] = {br0, br1, br2, br3};  // constant-indexed under unroll
    u64 a0 = 0, a1 = 0, a2 = 0, a3 = 0;
#pragma unroll
    for (int c = 0; c < 64; c += 4) {
      unsigned n0 = (unsigned)(brr[(c + 0) >> 4] >> (((c + 0) & 15) * 4)) & 15u;
      unsigned n1 = (unsigned)(brr[(c + 1) >> 4] >> (((c + 1) & 15) * 4)) & 15u;
      unsigned n2 = (unsigned)(brr[(c + 2) >> 4] >> (((c + 2) & 15) * 4)) & 15u;
      unsigned n3 = (unsigned)(brr[(c + 3) >> 4] >> (((c + 3) & 15) * 4)) & 15u;
      a0 ^= tbl[c + 0][n0][w];
      a1 ^= tbl[c + 1][n1][w];
      a2 ^= tbl[c + 2][n2][w];
      a3 ^= tbl[c + 3][n3][w];
    }
    u64 acc = (a0 ^ a1) ^ (a2 ^ a3);

    // a' = B*a ^ b : bit i = parity(popcount(Brow_i & a)) ^ b_i (waves 0..3)
    u64 mask = 0;
    if (tid < 256) {
      int p = __popcll(br0 & av0) + __popcll(br1 & av1) +
              __popcll(br2 & av2) + __popcll(br3 & av3);
      int bit = ((int)((bwc >> (i & 63)) & 1ull)) ^ (p & 1);
      mask = __ballot(bit);
    }
    __syncthreads();  // tbl/avec reads done before overwrite
    A[i][w] = acc;
    if (tid < 256 && (i & 63) == 0) avec[i >> 6] = mask;
    __syncthreads();
  }
}

// ---- 2) fold8: 8 INDEPENDENT blocks. Block g composes rounds [8g, 8g+8)
// (7 block-local composes; wb/nb from the previous launch — no fences, no
// tickets) and packs M_g -> fp4 A-fragments, c_g -> nf floats. ----
__global__ __launch_bounds__(1024) void fold8(const u64* __restrict__ wb,
                                              const u64* __restrict__ nb,
                                              uint32_t* __restrict__ wpk,
                                              float* __restrict__ nf) {
  __shared__ u64 A[256][5];       // padded (bank spread)
  __shared__ u64 tbl[64][16][5];
  __shared__ u64 avec[4];
  const int tid = threadIdx.x;
  const int g = blockIdx.x;  // chain/group 0..7

  fold_stream(A, tbl, avec, wb, nb, 8 * g, 8, tid, tid >> 8, tid & 255);

  // inline pack (R10-R15-verified): M_g bits -> fp4 A-fragments
#pragma unroll
  for (int it = 0; it < 2; ++it) {
    unsigned tg = (unsigned)it * 1024u + tid;  // row*8 + kwin, 2048 total
    unsigned kwin = tg & 7u, row = tg >> 3;
    uint32_t wd[4] = {0, 0, 0, 0};
#pragma unroll
    for (int n = 0; n < 32; ++n) {
      int k = (int)kwin * 32 + rho(n);
      uint32_t bit = (uint32_t)((A[row][k >> 6] >> (k & 63)) & 1ull);
      wd[n >> 3] |= (bit * 2u) << ((n & 7) * 4);  // fp4 e2m1: +1 -> 0b0010
    }
    unsigned mt = row >> 5, lhh = kwin & 1u, ks = kwin >> 1;
    unsigned lane = lhh * 32u + (row & 31u);
    *(uint4*)(wpk + ((((unsigned)g * 32u + mt * 4u + ks) * 64u + lane) << 2)) =
        make_uint4(wd[0], wd[1], wd[2], wd[3]);
  }
  if (tid < 256) {  // nf[g][mt][lh][j] = c_g[row(j,lh,mt)]
    unsigned j = tid & 15u, lhh = (tid >> 4) & 1u, mt = (unsigned)tid >> 5;
    unsigned row = mt * 32u + (j & 3u) + 8u * (j >> 2) + 4u * lhh;
    nf[(unsigned)g * 256u + tid] = (float)((avec[row >> 6] >> (row & 63u)) & 1ull);
  }
}

// ---- 3) hash8: the PROVEN R3 hash4 structure, 8 super-rounds. Initial state
// comes pre-bit-packed from spk: entry u32 bit m=k4c*4+comp. Expansion to the
// verified T layout: byteoff(k4c)=(k4c&1)*8+2*(k4c>>1) means lo-u64 (bytes
// 0-7) takes k4c even in m-order bits {0-3,8-11,16-19,24-27} -> compress to
// 16 bits -> spread16 -> nibble i bit 1; hi-u64 likewise from k4c odd. ----
__global__ __launch_bounds__(512, 4) void hash8(const uint32_t* __restrict__ wpk,
                                                const float* __restrict__ nf,
                                                const uint32_t* __restrict__ spk,
                                                float* __restrict__ out) {
  __shared__ uint8_t T[2][8][128][16];  // 32 KB
  const int t = threadIdx.x;
  const int wv = __builtin_amdgcn_readfirstlane(t >> 6);
  const int lane = t & 63;
  const int l31 = lane & 31;
  const int lh = lane >> 5;
  const int el0 = blockIdx.x * 128;

  // initial stage: spk bits -> sigma-ordered fp4 nibbles in T[0]
  {
    const uint32_t* sb = spk + (unsigned)blockIdx.x * 1024u;
#pragma unroll
    for (int it = 0; it < 2; ++it) {
      unsigned idx = (unsigned)it * 512u + t;
      uint32_t bits = sb[idx];
      unsigned KB = idx >> 7, el = idx & 127u;
      uint32_t pl = bits & 0x0F0F0F0Fu;
      pl = (pl | (pl >> 4)) & 0x00FF00FFu; pl = (pl | (pl >> 8)) & 0xFFFFu;
      uint32_t ph = (bits >> 4) & 0x0F0F0F0Fu;
      ph = (ph | (ph >> 4)) & 0x00FF00FFu; ph = (ph | (ph >> 8)) & 0xFFFFu;
      u64 lo = spread16(pl), hi = spread16(ph);
      *(uint4*)&T[0][KB][el][0] =
          make_uint4((uint32_t)lo, (uint32_t)(lo >> 32),
                     (uint32_t)hi, (uint32_t)(hi >> 32));
    }
  }
  __syncthreads();

  // prefetch round-0 A fragments + c C-init
  v4i ap[4];
  {
    const uint32_t* wb = wpk + ((wv * 4) << 8);
#pragma unroll
    for (int ks = 0; ks < 4; ++ks) ap[ks] = *(const v4i*)(wb + ks * 256 + lane * 4);
  }
  v16f NZ = *(const v16f*)(nf + (wv * 2 + lh) * 16);

  for (int r = 0; r < NSUP; ++r) {
    const int rb = r & 1, nx = rb ^ 1;
    v16f acc[4];
    __builtin_amdgcn_s_setprio(1);
#pragma unroll
    for (int ks = 0; ks < 4; ++ks) {
      // fp4 fmt uses only regs 0..3 of the 8-reg operand: 4..7 stay undef.
      v8i A8 = __builtin_shufflevector(ap[ks], ap[ks], 0, 1, 2, 3, -1, -1, -1, -1);
      const int kb = 2 * ks + lh;
#pragma unroll
      for (int tn = 0; tn < 4; ++tn) {
        v4i b4 = *(const v4i*)&T[rb][kb][tn * 32 + l31][0];  // conflict-free b128
        v8i B8 = __builtin_shufflevector(b4, b4, 0, 1, 2, 3, -1, -1, -1, -1);
        acc[tn] = __builtin_amdgcn_mfma_scale_f32_32x32x64_f8f6f4(
            A8, B8, (ks == 0) ? NZ : acc[tn], 4, 4, 0, 127, 0, 127);
      }
    }
    __builtin_amdgcn_s_setprio(0);

    // prefetch next round's A + NZ (r=7 wraps to 0 -> no OOB, dead value)
    {
      const int rn = (r + 1) & (NSUP - 1);
      const uint32_t* wb = wpk + (((rn * 8 + wv) * 4) << 8);
#pragma unroll
      for (int ks = 0; ks < 4; ++ks) ap[ks] = *(const v4i*)(wb + ks * 256 + lane * 4);
      NZ = *(const v16f*)(nf + ((rn * 8 + wv) * 2 + lh) * 16);
    }

    // epilogue: per-slot bias (exact) puts slot j's parity bit at mantissa
    // bit 4*(j&3)+1 == its target nibble-bit; mask + or-chain.
#pragma unroll
    for (int tn = 0; tn < 4; ++tn) {
#define PB(j)                                                          \
  (__builtin_bit_cast(uint32_t, acc[tn][j] + bias_q((j) & 3)) &        \
   (2u << (4 * ((j) & 3))))
      uint32_t u0 = PB(0) | PB(1) | PB(2) | PB(3);
      uint32_t u1 = PB(4) | PB(5) | PB(6) | PB(7);
      uint32_t u2 = PB(8) | PB(9) | PB(10) | PB(11);
      uint32_t u3 = PB(12) | PB(13) | PB(14) | PB(15);
#undef PB
      *(uint2*)&T[nx][wv][tn * 32 + l31][lh * 8] =
          make_uint2(u0 | (u1 << 16), u2 | (u3 << 16));
    }

    __syncthreads();  // single barrier/round (double-buffered state)
  }

  // ---- final unpack: 8 rounds (even) -> buf 0 holds the output ----
#pragma unroll
  for (int i = 0; i < 16; ++i) {
    unsigned flat = (unsigned)i * 512u + t;
    unsigned el = flat >> 6, k4 = flat & 63u;
    unsigned KB = k4 >> 3, k4c = k4 & 7u;
    unsigned byteoff = (k4c & 1u) * 8u + 2u * (k4c >> 1);
    uint32_t v = *(const uint16_t*)&T[0][KB][el][byteoff];
    float4 o = make_float4((float)((v >> 1) & 1u), (float)((v >> 5) & 1u),
                           (float)((v >> 9) & 1u), (float)((v >> 13) & 1u));
    ((float4*)(out + (size_t)el0 * 256))[flat] = o;
  }
}

extern "C" void kernel_launch(void* const* d_in, const int* in_sizes, int n_in,
                              void* d_out, int out_size, void* d_ws, size_t ws_size,
                              hipStream_t stream) {
  const float* sta = (const float*)d_in[0];  // [B, HIDDEN]
  const float* mat = (const float*)d_in[1];  // [ROUNDS, HIDDEN, HIDDEN]
  const float* noi = (const float*)d_in[2];  // [ROUNDS, HIDDEN]
  uint8_t* wsb = (uint8_t*)d_ws;             // needs ~2.9 MB

  uint32_t* spk = (uint32_t*)(wsb + SPK_OFF);
  u64* Wb       = (u64*)(wsb + WB_OFF);
  u64* nb       = (u64*)(wsb + NB_OFF);
  uint32_t* wpk = (uint32_t*)(wsb + WPK_OFF);
  float* nf     = (float*)(wsb + NF_OFF);

  bitpack<<<18496, 256, 0, stream>>>(mat, noi, sta, Wb, nb, spk);
  fold8<<<8, 1024, 0, stream>>>(Wb, nb, wpk, nf);
  hash8<<<512, 512, 0, stream>>>(wpk, nf, spk, (float*)d_out);
}

// Round 18
// 209.859 us; speedup vs baseline: 1.0939x; 1.0939x over previous
//
#include <hip/hip_runtime.h>
#include <stdint.h>

#define ROUNDS 64
#define HIDDEN 256
#define BATCH  65536
#define NSUP   16   // super-rounds: 16 chains of 4 rounds each (cost-model optimum)

typedef int   v4i  __attribute__((ext_vector_type(4)));
typedef int   v8i  __attribute__((ext_vector_type(8)));
typedef float v16f __attribute__((ext_vector_type(16)));
typedef unsigned long long u64;

// ============================================================================
// PARTIAL ALGEBRAIC COLLAPSE (math+packing verified exact R12-R17). Each round
// is affine over GF(2): s' = Whar s ^ n. 64 rounds -> 16 super-rounds of 4.
// Measured cost model (R13/R17): compose ~11us (block-local floor),
// hash round ~2.9us, hash I/O ~24us, fixed overhead ~95us, boundary ~22us.
// fold-critical=(64/N-1)*11, hash=24+N*2.9 -> minimum at NSUP=16.
// R18 combines only verified pieces: R17 bitpack (W+n+spk), R13 fold16,
// hash16 with R17's spk staging (saves hash's 64MB sta read + LDS scatter).
// NEVER: intra-kernel cross-block sync (~100-150us, R10-R12); fused per-CU
// bulk reads serialize (R14/R15); load->ballot chains serialize (R14).
// ============================================================================

// ws layout (bytes)
#define SPK_OFF  0u         // state bits [b=512][KB=8][el=128] u32 = 2 MB
#define WB_OFF   2097152u   // W bits [64][256][4] u64 = 512 KB
#define NB_OFF   2621440u   // n bits [64][4] u64      = 2 KB
#define WPK_OFF  2623488u   // fp4 A-frags [g=16][mt=8][ks=4][lane=64][16B] = 512 KB
#define NF_OFF   3147776u   // noise floats [g=16][mt=8][lh=2][j=16] f32 = 16 KB

// sigma: nibble slot n (0..31) within a 32-k chunk holds logical k-offset
// rho(n). Applied identically to M-pack and state-pack so it cancels.
__host__ __device__ constexpr int rho(int n) {
  return 4 * (n >> 4) + (n & 3) + 8 * ((n >> 2) & 3);
}

// Per-C-slot bias (epilogue v_add_f32, IEEE-exact; round-1 FAILED note: bias
// must stay OUTSIDE the MFMA C-init; c in {0,1} as C-init is proven).
__host__ __device__ constexpr float bias_q(int q) {
  return (q == 0) ? 6291456.0f   // 1.5*2^22 -> parity at bit 1
       : (q == 1) ? 393216.0f    // 1.5*2^18 -> bit 5
       : (q == 2) ? 24576.0f     // 1.5*2^14 -> bit 9
                  : 1536.0f;     // 1.5*2^10 -> bit 13
}

// spread16: p bit i -> u64 bit 4i+1 (nibble i, bit 1 == the fp4 "+1" bit).
__device__ __forceinline__ u64 spread16(uint32_t p) {
  u64 t = p;
  t = (t | (t << 24)) & 0x000000FF000000FFull;
  t = (t | (t << 12)) & 0x000F000F000F000Full;
  t = (t | (t << 6))  & 0x0303030303030303ull;
  t = (t | (t << 3))  & 0x1111111111111111ull;
  return t << 1;
}

// ---- 1) bitpack (R17-verified): W->bits, noise->bits, sta->bit-packed spk.
// spk entry (b,KB,el): u32, bit m = k4c*4+comp for float sta[el][KB*32+m].
__global__ __launch_bounds__(256) void bitpack(const float* __restrict__ mat,
                                               const float* __restrict__ noi,
                                               const float* __restrict__ sta,
                                               u64* __restrict__ wb,
                                               u64* __restrict__ nb,
                                               uint32_t* __restrict__ spk) {
  unsigned blk = blockIdx.x;
  if (blk < 16384u) {  // W bits
    unsigned tg = blk * 256u + threadIdx.x;
    u64 m = __ballot(mat[tg] != 0.f);
    if ((threadIdx.x & 63u) == 0u) wb[tg >> 6] = m;
    return;
  }
  if (blk < 16448u) {  // noise bits: 64*256
    unsigned tg = (blk - 16384u) * 256u + threadIdx.x;
    u64 m = __ballot(noi[tg] != 0.f);
    if ((threadIdx.x & 63u) == 0u) nb[tg >> 6] = m;
    return;
  }
  // sta bits: el = tg>>3, KB = tg&7; 8 independent float4 loads (MLP).
  unsigned tg = (blk - 16448u) * 256u + threadIdx.x;
  unsigned el = tg >> 3, KB = tg & 7u;
  const float4* s4 = (const float4*)(sta + (size_t)el * 256 + KB * 32);
  float4 f[8];
#pragma unroll
  for (int q = 0; q < 8; ++q) f[q] = s4[q];
  uint32_t bits = 0;
#pragma unroll
  for (int q = 0; q < 8; ++q) {
    bits |= (f[q].x != 0.f ? 1u : 0u) << (4 * q + 0);
    bits |= (f[q].y != 0.f ? 1u : 0u) << (4 * q + 1);
    bits |= (f[q].z != 0.f ? 1u : 0u) << (4 * q + 2);
    bits |= (f[q].w != 0.f ? 1u : 0u) << (4 * q + 3);
  }
  spk[(el >> 7) * 1024u + KB * 128u + (el & 127u)] = bits;
}

// ---- chain compose on one block's LDS state (R8-R17-verified algorithm,
// rolling 1-step register prefetch). (A,a) <- compose maps [base, base+count).
__device__ __forceinline__ void fold_stream(u64 (&A)[256][5],
                                            u64 (&tbl)[64][16][5],
                                            u64 (&avec)[4],
                                            const u64* __restrict__ inM,
                                            const u64* __restrict__ inV,
                                            int base, int count,
                                            int tid, int w, int i) {
  A[i][w] = inM[(size_t)base * 1024 + i * 4 + w];
  if (tid < 4) avec[tid] = inV[base * 4 + tid];
  u64 brP[4];
  u64 bwP;
  {  // prefetch step j=1's B row / vector word
    const u64* Bm = inM + (size_t)(base + 1) * 1024;
#pragma unroll
    for (int q = 0; q < 4; ++q) brP[q] = Bm[i * 4 + q];
    bwP = (tid < 256) ? inV[(size_t)(base + 1) * 4 + (i >> 6)] : 0ull;
  }
  __syncthreads();

  for (int j = 1; j < count; ++j) {
    const u64 br0 = brP[0], br1 = brP[1], br2 = brP[2], br3 = brP[3];
    const u64 bwc = bwP;
    if (j + 1 < count) {  // next step's loads hide under the table build
      const u64* Bm = inM + (size_t)(base + j + 1) * 1024;
#pragma unroll
      for (int q = 0; q < 4; ++q) brP[q] = Bm[i * 4 + q];
      bwP = (tid < 256) ? inV[(size_t)(base + j + 1) * 4 + (i >> 6)] : 0ull;
    }
    u64 av0 = avec[0], av1 = avec[1], av2 = avec[2], av3 = avec[3];

    // build 4-bit combination table over A's rows (contraction index k)
    {
      const int c = tid >> 4, m = tid & 15;  // 1024 entries, 1/thread
      u64 t0 = 0, t1 = 0, t2 = 0, t3 = 0;
#pragma unroll
      for (int jj = 0; jj < 4; ++jj)
        if (m & (1 << jj)) {
          t0 ^= A[4 * c + jj][0]; t1 ^= A[4 * c + jj][1];
          t2 ^= A[4 * c + jj][2]; t3 ^= A[4 * c + jj][3];
        }
      tbl[c][m][0] = t0; tbl[c][m][1] = t1; tbl[c][m][2] = t2; tbl[c][m][3] = t3;
    }
    __syncthreads();

    // R[i] = XOR_{k: B[i][k]=1} A[k], word w — 4-way ILP over the 64 gathers
    const u64 brr[4] = {br0, br1, br2, br3};  // constant-indexed under unroll
    u64 a0 = 0, a1 = 0, a2 = 0, a3 = 0;
#pragma unroll
    for (int c = 0; c < 64; c += 4) {
      unsigned n0 = (unsigned)(brr[(c + 0) >> 4] >> (((c + 0) & 15) * 4)) & 15u;
      unsigned n1 = (unsigned)(brr[(c + 1) >> 4] >> (((c + 1) & 15) * 4)) & 15u;
      unsigned n2 = (unsigned)(brr[(c + 2) >> 4] >> (((c + 2) & 15) * 4)) & 15u;
      unsigned n3 = (unsigned)(brr[(c + 3) >> 4] >> (((c + 3) & 15) * 4)) & 15u;
      a0 ^= tbl[c + 0][n0][w];
      a1 ^= tbl[c + 1][n1][w];
      a2 ^= tbl[c + 2][n2][w];
      a3 ^= tbl[c + 3][n3][w];
    }
    u64 acc = (a0 ^ a1) ^ (a2 ^ a3);

    // a' = B*a ^ b : bit i = parity(popcount(Brow_i & a)) ^ b_i (waves 0..3)
    u64 mask = 0;
    if (tid < 256) {
      int p = __popcll(br0 & av0) + __popcll(br1 & av1) +
              __popcll(br2 & av2) + __popcll(br3 & av3);
      int bit = ((int)((bwc >> (i & 63)) & 1ull)) ^ (p & 1);
      mask = __ballot(bit);
    }
    __syncthreads();  // tbl/avec reads done before overwrite
    A[i][w] = acc;
    if (tid < 256 && (i & 63) == 0) avec[i >> 6] = mask;
    __syncthreads();
  }
}

// ---- 2) fold16 (R13-verified): 16 INDEPENDENT blocks. Block g composes
// rounds [4g, 4g+4) (3 block-local composes) and packs M_g, c_g. ----
__global__ __launch_bounds__(1024) void fold16(const u64* __restrict__ wb,
                                               const u64* __restrict__ nb,
                                               uint32_t* __restrict__ wpk,
                                               float* __restrict__ nf) {
  __shared__ u64 A[256][5];       // padded (bank spread)
  __shared__ u64 tbl[64][16][5];
  __shared__ u64 avec[4];
  const int tid = threadIdx.x;
  const int g = blockIdx.x;  // chain/group 0..15

  fold_stream(A, tbl, avec, wb, nb, 4 * g, 4, tid, tid >> 8, tid & 255);

  // inline pack (R10-R17-verified): M_g bits -> fp4 A-fragments
#pragma unroll
  for (int it = 0; it < 2; ++it) {
    unsigned tg = (unsigned)it * 1024u + tid;  // row*8 + kwin, 2048 total
    unsigned kwin = tg & 7u, row = tg >> 3;
    uint32_t wd[4] = {0, 0, 0, 0};
#pragma unroll
    for (int n = 0; n < 32; ++n) {
      int k = (int)kwin * 32 + rho(n);
      uint32_t bit = (uint32_t)((A[row][k >> 6] >> (k & 63)) & 1ull);
      wd[n >> 3] |= (bit * 2u) << ((n & 7) * 4);  // fp4 e2m1: +1 -> 0b0010
    }
    unsigned mt = row >> 5, lhh = kwin & 1u, ks = kwin >> 1;
    unsigned lane = lhh * 32u + (row & 31u);
    *(uint4*)(wpk + ((((unsigned)g * 32u + mt * 4u + ks) * 64u + lane) << 2)) =
        make_uint4(wd[0], wd[1], wd[2], wd[3]);
  }
  if (tid < 256) {  // nf[g][mt][lh][j] = c_g[row(j,lh,mt)]
    unsigned j = tid & 15u, lhh = (tid >> 4) & 1u, mt = (unsigned)tid >> 5;
    unsigned row = mt * 32u + (j & 3u) + 8u * (j >> 2) + 4u * lhh;
    nf[(unsigned)g * 256u + tid] = (float)((avec[row >> 6] >> (row & 63u)) & 1ull);
  }
}

// ---- 3) hash16: R13-verified 16-super-round structure with R17-verified
// spk-based T[0] staging. Per round: S <- parity(M_g S + c_g). fp4 MFMA
// 32x32x64, K=256 in 4 steps, c_g C-init, bias-trick epilogue, double-
// buffered LDS, round-ahead A/NZ prefetch. 512 thr, 128 el/block. ----
__global__ __launch_bounds__(512, 4) void hash16(const uint32_t* __restrict__ wpk,
                                                 const float* __restrict__ nf,
                                                 const uint32_t* __restrict__ spk,
                                                 float* __restrict__ out) {
  __shared__ uint8_t T[2][8][128][16];  // 32 KB
  const int t = threadIdx.x;
  const int wv = __builtin_amdgcn_readfirstlane(t >> 6);
  const int lane = t & 63;
  const int l31 = lane & 31;
  const int lh = lane >> 5;
  const int el0 = blockIdx.x * 128;

  // initial stage (R17-verified): spk bits -> sigma-ordered fp4 nibbles.
  // byteoff(k4c)=(k4c&1)*8+2*(k4c>>1): lo-u64 takes k4c even (m-bits
  // {0-3,8-11,16-19,24-27} -> compress -> spread16); hi-u64 takes k4c odd.
  {
    const uint32_t* sb = spk + (unsigned)blockIdx.x * 1024u;
#pragma unroll
    for (int it = 0; it < 2; ++it) {
      unsigned idx = (unsigned)it * 512u + t;
      uint32_t bits = sb[idx];
      unsigned KB = idx >> 7, el = idx & 127u;
      uint32_t pl = bits & 0x0F0F0F0Fu;
      pl = (pl | (pl >> 4)) & 0x00FF00FFu; pl = (pl | (pl >> 8)) & 0xFFFFu;
      uint32_t ph = (bits >> 4) & 0x0F0F0F0Fu;
      ph = (ph | (ph >> 4)) & 0x00FF00FFu; ph = (ph | (ph >> 8)) & 0xFFFFu;
      u64 lo = spread16(pl), hi = spread16(ph);
      *(uint4*)&T[0][KB][el][0] =
          make_uint4((uint32_t)lo, (uint32_t)(lo >> 32),
                     (uint32_t)hi, (uint32_t)(hi >> 32));
    }
  }
  __syncthreads();

  // prefetch round-0 A fragments + c C-init
  v4i ap[4];
  {
    const uint32_t* wb = wpk + ((wv * 4) << 8);
#pragma unroll
    for (int ks = 0; ks < 4; ++ks) ap[ks] = *(const v4i*)(wb + ks * 256 + lane * 4);
  }
  v16f NZ = *(const v16f*)(nf + (wv * 2 + lh) * 16);

  for (int r = 0; r < NSUP; ++r) {
    const int rb = r & 1, nx = rb ^ 1;
    v16f acc[4];
    __builtin_amdgcn_s_setprio(1);
#pragma unroll
    for (int ks = 0; ks < 4; ++ks) {
      // fp4 fmt uses only regs 0..3 of the 8-reg operand: 4..7 stay undef.
      v8i A8 = __builtin_shufflevector(ap[ks], ap[ks], 0, 1, 2, 3, -1, -1, -1, -1);
      const int kb = 2 * ks + lh;
#pragma unroll
      for (int tn = 0; tn < 4; ++tn) {
        v4i b4 = *(const v4i*)&T[rb][kb][tn * 32 + l31][0];  // conflict-free b128
        v8i B8 = __builtin_shufflevector(b4, b4, 0, 1, 2, 3, -1, -1, -1, -1);
        acc[tn] = __builtin_amdgcn_mfma_scale_f32_32x32x64_f8f6f4(
            A8, B8, (ks == 0) ? NZ : acc[tn], 4, 4, 0, 127, 0, 127);
      }
    }
    __builtin_amdgcn_s_setprio(0);

    // prefetch next round's A + NZ (r=15 wraps to 0 -> no OOB, dead value)
    {
      const int rn = (r + 1) & (NSUP - 1);
      const uint32_t* wb = wpk + (((rn * 8 + wv) * 4) << 8);
#pragma unroll
      for (int ks = 0; ks < 4; ++ks) ap[ks] = *(const v4i*)(wb + ks * 256 + lane * 4);
      NZ = *(const v16f*)(nf + ((rn * 8 + wv) * 2 + lh) * 16);
    }

    // epilogue: per-slot bias (exact) puts slot j's parity bit at mantissa
    // bit 4*(j&3)+1 == its target nibble-bit; mask + or-chain.
#pragma unroll
    for (int tn = 0; tn < 4; ++tn) {
#define PB(j)                                                          \
  (__builtin_bit_cast(uint32_t, acc[tn][j] + bias_q((j) & 3)) &        \
   (2u << (4 * ((j) & 3))))
      uint32_t u0 = PB(0) | PB(1) | PB(2) | PB(3);
      uint32_t u1 = PB(4) | PB(5) | PB(6) | PB(7);
      uint32_t u2 = PB(8) | PB(9) | PB(10) | PB(11);
      uint32_t u3 = PB(12) | PB(13) | PB(14) | PB(15);
#undef PB
      *(uint2*)&T[nx][wv][tn * 32 + l31][lh * 8] =
          make_uint2(u0 | (u1 << 16), u2 | (u3 << 16));
    }

    __syncthreads();  // single barrier/round (double-buffered state)
  }

  // ---- final unpack: 16 rounds (even) -> buf 0 holds the output ----
#pragma unroll
  for (int i = 0; i < 16; ++i) {
    unsigned flat = (unsigned)i * 512u + t;
    unsigned el = flat >> 6, k4 = flat & 63u;
    unsigned KB = k4 >> 3, k4c = k4 & 7u;
    unsigned byteoff = (k4c & 1u) * 8u + 2u * (k4c >> 1);
    uint32_t v = *(const uint16_t*)&T[0][KB][el][byteoff];
    float4 o = make_float4((float)((v >> 1) & 1u), (float)((v >> 5) & 1u),
                           (float)((v >> 9) & 1u), (float)((v >> 13) & 1u));
    ((float4*)(out + (size_t)el0 * 256))[flat] = o;
  }
}

extern "C" void kernel_launch(void* const* d_in, const int* in_sizes, int n_in,
                              void* d_out, int out_size, void* d_ws, size_t ws_size,
                              hipStream_t stream) {
  const float* sta = (const float*)d_in[0];  // [B, HIDDEN]
  const float* mat = (const float*)d_in[1];  // [ROUNDS, HIDDEN, HIDDEN]
  const float* noi = (const float*)d_in[2];  // [ROUNDS, HIDDEN]
  uint8_t* wsb = (uint8_t*)d_ws;             // needs ~3.2 MB

  uint32_t* spk = (uint32_t*)(wsb + SPK_OFF);
  u64* Wb       = (u64*)(wsb + WB_OFF);
  u64* nb       = (u64*)(wsb + NB_OFF);
  uint32_t* wpk = (uint32_t*)(wsb + WPK_OFF);
  float* nf     = (float*)(wsb + NF_OFF);

  bitpack<<<18496, 256, 0, stream>>>(mat, noi, sta, Wb, nb, spk);
  fold16<<<16, 1024, 0, stream>>>(Wb, nb, wpk, nf);
  hash16<<<512, 512, 0, stream>>>(wpk, nf, spk, (float*)d_out);
}